// Round 1
// baseline (90.272 us; speedup 1.0000x reference)
//
#include <hip/hip_runtime.h>

// Problem constants (derivable from sizes, but D is fixed by the model).
#define DDIM 256
#define WAVES_PER_BLOCK 4

// One wave (64 lanes) per mention. Lane l owns columns [4l, 4l+4).
// Row load: 64 lanes x float4 = 1024 B = one full contiguous enc_seq row.
__global__ void mention_accum_kernel(const float* __restrict__ enc,
                                     const int* __restrict__ info,
                                     float* __restrict__ ent_sum,  // [E][D] (= d_out)
                                     float* __restrict__ cnt,      // [E]    (= d_ws)
                                     int M) {
    int wave = blockIdx.x * WAVES_PER_BLOCK + (threadIdx.x >> 6);
    if (wave >= M) return;
    int lane = threadIdx.x & 63;

    const int* r = info + (size_t)wave * 4;   // [eid, etype, start, end]
    int eid   = r[0];
    int start = r[2];
    int end   = r[3];
    int len   = end - start;
    if (len <= 0) {  // not expected (lens in [1,16]); still count the mention
        if (lane == 0) atomicAdd(cnt + eid, 1.0f);
        return;
    }

    const float4* base = reinterpret_cast<const float4*>(enc)
                         + (size_t)start * (DDIM / 4) + lane;
    float4 acc = make_float4(0.f, 0.f, 0.f, 0.f);
    for (int i = 0; i < len; ++i) {
        float4 v = base[(size_t)i * (DDIM / 4)];
        acc.x += v.x; acc.y += v.y; acc.z += v.z; acc.w += v.w;
    }
    float inv = 1.0f / (float)len;

    float* dst = ent_sum + (size_t)eid * DDIM + lane * 4;
    atomicAdd(dst + 0, acc.x * inv);
    atomicAdd(dst + 1, acc.y * inv);
    atomicAdd(dst + 2, acc.z * inv);
    atomicAdd(dst + 3, acc.w * inv);
    if (lane == 0) atomicAdd(cnt + eid, 1.0f);
}

__global__ void finalize_kernel(float* __restrict__ out,
                                const float* __restrict__ cnt,
                                int n) {
    int t = blockIdx.x * blockDim.x + threadIdx.x;
    if (t >= n) return;
    float c = cnt[t >> 8];               // t/DDIM
    out[t] = out[t] / fmaxf(c, 1.0f);
}

extern "C" void kernel_launch(void* const* d_in, const int* in_sizes, int n_in,
                              void* d_out, int out_size, void* d_ws, size_t ws_size,
                              hipStream_t stream) {
    const float* enc  = (const float*)d_in[0];
    const int*   info = (const int*)d_in[1];   // int64 in source, but JAX x64 is off -> int32

    int M = in_sizes[1] / 4;
    int E = out_size / DDIM;

    float* out = (float*)d_out;
    float* cnt = (float*)d_ws;

    // d_out / d_ws are poisoned and never re-poisoned between replays.
    hipMemsetAsync(d_out, 0, (size_t)out_size * sizeof(float), stream);
    hipMemsetAsync(d_ws, 0, (size_t)E * sizeof(float), stream);

    int blocks = (M + WAVES_PER_BLOCK - 1) / WAVES_PER_BLOCK;
    mention_accum_kernel<<<blocks, 64 * WAVES_PER_BLOCK, 0, stream>>>(
        enc, info, out, cnt, M);

    finalize_kernel<<<(out_size + 255) / 256, 256, 0, stream>>>(out, cnt, out_size);
}

// Round 2
// 43.522 us; speedup vs baseline: 2.0742x; 2.0742x over previous
//
#include <hip/hip_runtime.h>

#define DDIM 256
#define WAVES_PER_BLOCK 4

// ---------- Path A (preferred): group-by-entity, zero output atomics ----------

// Scatter mention ids into per-entity buckets. Only M (=20000) int atomics.
__global__ void scatter_kernel(const int* __restrict__ info,
                               int* __restrict__ cursor,   // [E], pre-zeroed
                               int* __restrict__ bucket,   // [E][M] strided
                               int M) {
    int m = blockIdx.x * blockDim.x + threadIdx.x;
    if (m >= M) return;
    int eid = info[(size_t)m * 4];
    int pos = atomicAdd(cursor + eid, 1);
    bucket[(size_t)eid * M + pos] = m;
}

// One wave per entity: accumulate mention means in registers, write 1 KB once.
__global__ void entity_kernel(const float* __restrict__ enc,
                              const int* __restrict__ info,
                              const int* __restrict__ cursor,  // counts
                              const int* __restrict__ bucket,
                              float* __restrict__ out,
                              int M, int E) {
    int e = blockIdx.x * WAVES_PER_BLOCK + (threadIdx.x >> 6);
    if (e >= E) return;
    int lane = threadIdx.x & 63;

    int cnt = cursor[e];
    const int* bk = bucket + (size_t)e * M;

    float4 eacc = make_float4(0.f, 0.f, 0.f, 0.f);
    for (int j = 0; j < cnt; ++j) {
        int m = bk[j];
        const int* r = info + (size_t)m * 4;   // [eid, etype, start, end]
        int start = r[2];
        int len   = r[3] - start;
        const float4* base = reinterpret_cast<const float4*>(enc)
                             + (size_t)start * (DDIM / 4) + lane;
        float4 macc = make_float4(0.f, 0.f, 0.f, 0.f);
        for (int i = 0; i < len; ++i) {
            float4 v = base[(size_t)i * (DDIM / 4)];
            macc.x += v.x; macc.y += v.y; macc.z += v.z; macc.w += v.w;
        }
        float inv = (len > 0) ? 1.0f / (float)len : 0.0f;
        eacc.x += macc.x * inv; eacc.y += macc.y * inv;
        eacc.z += macc.z * inv; eacc.w += macc.w * inv;
    }
    float invc = 1.0f / fmaxf((float)cnt, 1.0f);
    float4 res = make_float4(eacc.x * invc, eacc.y * invc,
                             eacc.z * invc, eacc.w * invc);
    reinterpret_cast<float4*>(out + (size_t)e * DDIM)[lane] = res;
}

// ---------- Path B (fallback if ws too small): round-1 atomic version ----------

__global__ void mention_accum_kernel(const float* __restrict__ enc,
                                     const int* __restrict__ info,
                                     float* __restrict__ ent_sum,
                                     float* __restrict__ cnt,
                                     int M) {
    int wave = blockIdx.x * WAVES_PER_BLOCK + (threadIdx.x >> 6);
    if (wave >= M) return;
    int lane = threadIdx.x & 63;
    const int* r = info + (size_t)wave * 4;
    int eid = r[0], start = r[2], len = r[3] - r[2];
    if (len <= 0) {
        if (lane == 0) atomicAdd(cnt + eid, 1.0f);
        return;
    }
    const float4* base = reinterpret_cast<const float4*>(enc)
                         + (size_t)start * (DDIM / 4) + lane;
    float4 acc = make_float4(0.f, 0.f, 0.f, 0.f);
    for (int i = 0; i < len; ++i) {
        float4 v = base[(size_t)i * (DDIM / 4)];
        acc.x += v.x; acc.y += v.y; acc.z += v.z; acc.w += v.w;
    }
    float inv = 1.0f / (float)len;
    float* dst = ent_sum + (size_t)eid * DDIM + lane * 4;
    atomicAdd(dst + 0, acc.x * inv);
    atomicAdd(dst + 1, acc.y * inv);
    atomicAdd(dst + 2, acc.z * inv);
    atomicAdd(dst + 3, acc.w * inv);
    if (lane == 0) atomicAdd(cnt + eid, 1.0f);
}

__global__ void finalize_kernel(float* __restrict__ out,
                                const float* __restrict__ cnt, int n) {
    int t = blockIdx.x * blockDim.x + threadIdx.x;
    if (t >= n) return;
    out[t] = out[t] / fmaxf(cnt[t >> 8], 1.0f);
}

extern "C" void kernel_launch(void* const* d_in, const int* in_sizes, int n_in,
                              void* d_out, int out_size, void* d_ws, size_t ws_size,
                              hipStream_t stream) {
    const float* enc  = (const float*)d_in[0];
    const int*   info = (const int*)d_in[1];   // int64 in source, but JAX x64 off -> int32

    int M = in_sizes[1] / 4;
    int E = out_size / DDIM;
    float* out = (float*)d_out;

    size_t cursor_bytes = 16384;  // E ints, padded/aligned
    size_t need = cursor_bytes + (size_t)E * (size_t)M * sizeof(int);

    if (ws_size >= need) {
        int* cursor = (int*)d_ws;
        int* bucket = (int*)((char*)d_ws + cursor_bytes);

        hipMemsetAsync(cursor, 0, (size_t)E * sizeof(int), stream);
        scatter_kernel<<<(M + 255) / 256, 256, 0, stream>>>(info, cursor, bucket, M);
        int blocks = (E + WAVES_PER_BLOCK - 1) / WAVES_PER_BLOCK;
        entity_kernel<<<blocks, 64 * WAVES_PER_BLOCK, 0, stream>>>(
            enc, info, cursor, bucket, out, M, E);
    } else {
        float* cnt = (float*)d_ws;
        hipMemsetAsync(d_out, 0, (size_t)out_size * sizeof(float), stream);
        hipMemsetAsync(cnt, 0, (size_t)E * sizeof(float), stream);
        int blocks = (M + WAVES_PER_BLOCK - 1) / WAVES_PER_BLOCK;
        mention_accum_kernel<<<blocks, 64 * WAVES_PER_BLOCK, 0, stream>>>(
            enc, info, out, cnt, M);
        finalize_kernel<<<(out_size + 255) / 256, 256, 0, stream>>>(out, cnt, out_size);
    }
}

// Round 3
// 40.780 us; speedup vs baseline: 2.2136x; 1.0672x over previous
//
#include <hip/hip_runtime.h>

#define DDIM 256
#define WAVES_PER_BLOCK 4
#define HALVES 2   // waves per entity; each wave owns DDIM/HALVES columns

// ---------- Path A: group-by-entity, zero output atomics ----------

// Scatter mention ids into per-entity buckets. Only M (=20000) int atomics.
__global__ void scatter_kernel(const int* __restrict__ info,
                               int* __restrict__ cursor,   // [E], pre-zeroed
                               int* __restrict__ bucket,   // [E][M] strided
                               int M) {
    int m = blockIdx.x * blockDim.x + threadIdx.x;
    if (m >= M) return;
    int eid = info[(size_t)m * 4];
    int pos = atomicAdd(cursor + eid, 1);
    bucket[(size_t)eid * M + pos] = m;
}

// 2 waves per entity (column halves). Headers fetched in parallel across
// lanes then shfl-broadcast, so row gathers stream with no dependent chain.
__global__ void entity_kernel(const float* __restrict__ enc,
                              const int* __restrict__ info,
                              const int* __restrict__ cursor,  // counts
                              const int* __restrict__ bucket,
                              float* __restrict__ out,
                              int M, int E) {
    int gw = blockIdx.x * WAVES_PER_BLOCK + (threadIdx.x >> 6);
    int e    = gw / HALVES;
    int half = gw % HALVES;
    if (e >= E) return;
    int lane = threadIdx.x & 63;

    int cnt = cursor[e];
    const int* bk = bucket + (size_t)e * M;

    const int COLS2 = DDIM / 2;          // row length in float2
    const int HW    = DDIM / (2 * HALVES); // float2 elems per wave (=64)

    float2 eacc = make_float2(0.f, 0.f);
    for (int j0 = 0; j0 < cnt; j0 += 64) {
        int nj = min(cnt - j0, 64);
        int mystart = 0, mylen = 0;
        if (lane < nj) {
            int m = bk[j0 + lane];
            int4 r = reinterpret_cast<const int4*>(info)[m]; // [eid,etype,start,end]
            mystart = r.z;
            mylen   = r.w - r.z;
        }
        for (int j = 0; j < nj; ++j) {
            int start = __shfl(mystart, j);
            int len   = __shfl(mylen, j);
            const float2* base = reinterpret_cast<const float2*>(enc)
                                 + (size_t)start * COLS2 + half * HW + lane;
            float2 macc = make_float2(0.f, 0.f);
            #pragma unroll 4
            for (int i = 0; i < len; ++i) {
                float2 v = base[(size_t)i * COLS2];
                macc.x += v.x; macc.y += v.y;
            }
            float inv = (len > 0) ? 1.0f / (float)len : 0.0f;
            eacc.x += macc.x * inv;
            eacc.y += macc.y * inv;
        }
    }
    float invc = 1.0f / fmaxf((float)cnt, 1.0f);
    float2 res = make_float2(eacc.x * invc, eacc.y * invc);
    reinterpret_cast<float2*>(out)[(size_t)e * COLS2 + half * HW + lane] = res;
}

// ---------- Path B (fallback if ws too small): atomic version ----------

__global__ void mention_accum_kernel(const float* __restrict__ enc,
                                     const int* __restrict__ info,
                                     float* __restrict__ ent_sum,
                                     float* __restrict__ cnt,
                                     int M) {
    int wave = blockIdx.x * WAVES_PER_BLOCK + (threadIdx.x >> 6);
    if (wave >= M) return;
    int lane = threadIdx.x & 63;
    const int* r = info + (size_t)wave * 4;
    int eid = r[0], start = r[2], len = r[3] - r[2];
    if (len <= 0) {
        if (lane == 0) atomicAdd(cnt + eid, 1.0f);
        return;
    }
    const float4* base = reinterpret_cast<const float4*>(enc)
                         + (size_t)start * (DDIM / 4) + lane;
    float4 acc = make_float4(0.f, 0.f, 0.f, 0.f);
    for (int i = 0; i < len; ++i) {
        float4 v = base[(size_t)i * (DDIM / 4)];
        acc.x += v.x; acc.y += v.y; acc.z += v.z; acc.w += v.w;
    }
    float inv = 1.0f / (float)len;
    float* dst = ent_sum + (size_t)eid * DDIM + lane * 4;
    atomicAdd(dst + 0, acc.x * inv);
    atomicAdd(dst + 1, acc.y * inv);
    atomicAdd(dst + 2, acc.z * inv);
    atomicAdd(dst + 3, acc.w * inv);
    if (lane == 0) atomicAdd(cnt + eid, 1.0f);
}

__global__ void finalize_kernel(float* __restrict__ out,
                                const float* __restrict__ cnt, int n) {
    int t = blockIdx.x * blockDim.x + threadIdx.x;
    if (t >= n) return;
    out[t] = out[t] / fmaxf(cnt[t >> 8], 1.0f);
}

extern "C" void kernel_launch(void* const* d_in, const int* in_sizes, int n_in,
                              void* d_out, int out_size, void* d_ws, size_t ws_size,
                              hipStream_t stream) {
    const float* enc  = (const float*)d_in[0];
    const int*   info = (const int*)d_in[1];   // int64 in source, but JAX x64 off -> int32

    int M = in_sizes[1] / 4;
    int E = out_size / DDIM;
    float* out = (float*)d_out;

    size_t cursor_bytes = 16384;  // E ints, padded/aligned
    size_t need = cursor_bytes + (size_t)E * (size_t)M * sizeof(int);

    if (ws_size >= need) {
        int* cursor = (int*)d_ws;
        int* bucket = (int*)((char*)d_ws + cursor_bytes);

        hipMemsetAsync(cursor, 0, (size_t)E * sizeof(int), stream);
        scatter_kernel<<<(M + 255) / 256, 256, 0, stream>>>(info, cursor, bucket, M);
        int gwaves = E * HALVES;
        int blocks = (gwaves + WAVES_PER_BLOCK - 1) / WAVES_PER_BLOCK;
        entity_kernel<<<blocks, 64 * WAVES_PER_BLOCK, 0, stream>>>(
            enc, info, cursor, bucket, out, M, E);
    } else {
        float* cnt = (float*)d_ws;
        hipMemsetAsync(d_out, 0, (size_t)out_size * sizeof(float), stream);
        hipMemsetAsync(cnt, 0, (size_t)E * sizeof(float), stream);
        int blocks = (M + WAVES_PER_BLOCK - 1) / WAVES_PER_BLOCK;
        mention_accum_kernel<<<blocks, 64 * WAVES_PER_BLOCK, 0, stream>>>(
            enc, info, out, cnt, M);
        finalize_kernel<<<(out_size + 255) / 256, 256, 0, stream>>>(out, cnt, out_size);
    }
}